// Round 4
// baseline (192.438 us; speedup 1.0000x reference)
//
#include <hip/hip_runtime.h>

#define B_ 8
#define N_ 8192
#define S_ 2048
#define D_ 256
#define EPS_ 1e-8f
#define TILE_Q 64
#define NTHR 512
#define NCH 8
#define CHUNK (S_ / NCH)   /* 256 candidates per wave */
#define NPAIR (S_ / 2)     /* 1024 candidate pairs */

typedef float f32x2 __attribute__((ext_vector_type(2)));

// Branchless stable top-3 insert, med3 network. Sorted invariant d0<=d1<=d2.
// Strict '<' => incumbent (earlier index) wins ties, matching jax.lax.top_k.
__device__ __forceinline__ void insert3(float dd, int s,
                                        float& d0, float& d1, float& d2,
                                        int& i0, int& i1, int& i2) {
    bool ca = dd < d0;
    bool cb = dd < d1;
    bool cc = dd < d2;
    int i2n = cb ? i1 : (cc ? s : i2);
    int i1n = ca ? i0 : (cb ? s : i1);
    int i0n = ca ? s : i0;
    d2 = fminf(d2, fmaxf(d1, dd));
    d1 = __builtin_amdgcn_fmed3f(d0, d1, dd);
    d0 = fminf(d0, dd);
    i0 = i0n; i1 = i1n; i2 = i2n;
}

__global__ __launch_bounds__(NTHR, 8) void fp_interp_kernel(
    const float* __restrict__ xyz1,     // [B,3,N]
    const float* __restrict__ xyz2,     // [B,3,S]
    const float* __restrict__ points2,  // [B,S,D]
    float* __restrict__ out)            // [B,N,D]
{
    __shared__ f32x2 s_x[NPAIR];             // 8 KB  (x[2p], x[2p+1])
    __shared__ f32x2 s_y[NPAIR];             // 8 KB
    __shared__ f32x2 s_z[NPAIR];             // 8 KB
    __shared__ float s_pd[NCH][3][TILE_Q];   // partial top-3 dists
    __shared__ int   s_pi[NCH][3][TILE_Q];   // partial top-3 idx
    __shared__ float s_w[3][TILE_Q];
    __shared__ int   s_idx[3][TILE_Q];

    const int blocksPerBatch = N_ / TILE_Q;  // 128
    const int b  = blockIdx.x / blocksPerBatch;
    const int n0 = (blockIdx.x % blocksPerBatch) * TILE_Q;
    const int t = threadIdx.x;
    const int wave = t >> 6, lane = t & 63;

    // Stage xyz2 as SoA float2 pairs (coalesced 8B global loads).
    const float* x2 = xyz2 + (size_t)b * 3 * S_;
    const f32x2* gx = (const f32x2*)x2;
    const f32x2* gy = (const f32x2*)(x2 + S_);
    const f32x2* gz = (const f32x2*)(x2 + 2 * S_);
    for (int p = t; p < NPAIR; p += NTHR) {
        s_x[p] = gx[p]; s_y[p] = gy[p]; s_z[p] = gz[p];
    }
    __syncthreads();

    // Phase A: wave w scans its 128-pair chunk for all 64 queries (lane<->query).
    // LDS reads are wave-uniform -> ds_read_b64 broadcast, 0 conflicts.
    // Distances in packed fp32: 6 v_pk_* per pair = 3 VALU/candidate.
    const int n = n0 + lane;
    const float* x1 = xyz1 + (size_t)b * 3 * N_;
    const float ax = x1[n], ay = x1[N_ + n], az = x1[2 * N_ + n];
    const f32x2 axv = {ax, ax}, ayv = {ay, ay}, azv = {az, az};

    float d0 = __builtin_inff(), d1 = __builtin_inff(), d2 = __builtin_inff();
    int i0 = 0, i1 = 0, i2 = 0;
    const int pbeg = wave * (CHUNK / 2);
    #pragma unroll 8
    for (int p = pbeg; p < pbeg + CHUNK / 2; ++p) {
        f32x2 dx = axv - s_x[p];
        f32x2 dy = ayv - s_y[p];
        f32x2 dz = azv - s_z[p];
        f32x2 dd = __builtin_elementwise_fma(
            dx, dx, __builtin_elementwise_fma(dy, dy, dz * dz));
        // even index first, odd second: preserves ascending-index stability
        insert3(dd.x, 2 * p,     d0, d1, d2, i0, i1, i2);
        insert3(dd.y, 2 * p + 1, d0, d1, d2, i0, i1, i2);
    }
    s_pd[wave][0][lane] = d0; s_pd[wave][1][lane] = d1; s_pd[wave][2][lane] = d2;
    s_pi[wave][0][lane] = i0; s_pi[wave][1][lane] = i1; s_pi[wave][2][lane] = i2;
    __syncthreads();

    // Phase B: merge 8 chunk-triples per query (chunk order => index-stable).
    if (t < TILE_Q) {
        float e0 = __builtin_inff(), e1 = __builtin_inff(), e2 = __builtin_inff();
        int j0 = 0, j1 = 0, j2 = 0;
        #pragma unroll
        for (int c = 0; c < NCH; ++c) {
            #pragma unroll
            for (int k = 0; k < 3; ++k)
                insert3(s_pd[c][k][t], s_pi[c][k][t], e0, e1, e2, j0, j1, j2);
        }
        float r0 = __fdiv_rn(1.0f, __fadd_rn(e0, EPS_));
        float r1 = __fdiv_rn(1.0f, __fadd_rn(e1, EPS_));
        float r2 = __fdiv_rn(1.0f, __fadd_rn(e2, EPS_));
        float rs = __fadd_rn(__fadd_rn(r0, r1), r2);
        s_w[0][t] = __fdiv_rn(r0, rs);
        s_w[1][t] = __fdiv_rn(r1, rs);
        s_w[2][t] = __fdiv_rn(r2, rs);
        s_idx[0][t] = j0; s_idx[1][t] = j1; s_idx[2][t] = j2;
    }
    __syncthreads();

    // Phase C: gather + weighted sum. One wave per query row; 64 lanes x float4
    // covers D=256. points2 slice is 2 MB/batch -> L2-resident.
    const float* p2 = points2 + (size_t)b * S_ * D_;
    float* op = out + ((size_t)b * N_ + n0) * D_;
    for (int q = wave; q < TILE_Q; q += NCH) {
        float w0 = s_w[0][q], w1 = s_w[1][q], w2 = s_w[2][q];
        const float4* f0 = (const float4*)(p2 + (size_t)s_idx[0][q] * D_) + lane;
        const float4* f1 = (const float4*)(p2 + (size_t)s_idx[1][q] * D_) + lane;
        const float4* f2 = (const float4*)(p2 + (size_t)s_idx[2][q] * D_) + lane;
        float4 a0 = *f0, a1 = *f1, a2 = *f2;
        float4 r;
        r.x = w0 * a0.x + w1 * a1.x + w2 * a2.x;
        r.y = w0 * a0.y + w1 * a1.y + w2 * a2.y;
        r.z = w0 * a0.z + w1 * a1.z + w2 * a2.z;
        r.w = w0 * a0.w + w1 * a1.w + w2 * a2.w;
        *((float4*)(op + (size_t)q * D_) + lane) = r;
    }
}

extern "C" void kernel_launch(void* const* d_in, const int* in_sizes, int n_in,
                              void* d_out, int out_size, void* d_ws, size_t ws_size,
                              hipStream_t stream) {
    const float* xyz1    = (const float*)d_in[0];
    const float* xyz2    = (const float*)d_in[1];
    // d_in[2] = points1 is unused by the reference output.
    const float* points2 = (const float*)d_in[3];
    float* out = (float*)d_out;

    dim3 grid(B_ * (N_ / TILE_Q));  // 1024 blocks, 4 per CU at 512 thr
    dim3 block(NTHR);
    fp_interp_kernel<<<grid, block, 0, stream>>>(xyz1, xyz2, points2, out);
}

// Round 5
// 188.164 us; speedup vs baseline: 1.0227x; 1.0227x over previous
//
#include <hip/hip_runtime.h>

#define B_ 8
#define N_ 8192
#define S_ 2048
#define D_ 256
#define EPS_ 1e-8f
#define TILE_Q 64
#define NTHR 512
#define NCH 8
#define CHUNK (S_ / NCH)   /* 256 candidates per wave */
#define HPAIR 64           /* pairs per half-chunk (128 candidates) */

typedef float f32x2 __attribute__((ext_vector_type(2)));

// Branchless stable top-3 insert, med3 network. Sorted invariant d0<=d1<=d2.
// Strict '<' => incumbent (earlier index) wins ties, matching jax.lax.top_k.
__device__ __forceinline__ void insert3(float dd, int s,
                                        float& d0, float& d1, float& d2,
                                        int& i0, int& i1, int& i2) {
    bool ca = dd < d0;
    bool cb = dd < d1;
    bool cc = dd < d2;
    int i2n = cb ? i1 : (cc ? s : i2);
    int i1n = ca ? i0 : (cb ? s : i1);
    int i0n = ca ? s : i0;
    d2 = fminf(d2, fmaxf(d1, dd));
    d1 = __builtin_amdgcn_fmed3f(d0, d1, dd);
    d0 = fminf(d0, dd);
    i0 = i0n; i1 = i1n; i2 = i2n;
}

__global__ __launch_bounds__(NTHR, 8) void fp_interp_kernel(
    const float* __restrict__ xyz1,     // [B,3,N]
    const float* __restrict__ xyz2,     // [B,3,S]
    const float* __restrict__ points2,  // [B,S,D]
    float* __restrict__ out)            // [B,N,D]
{
    __shared__ float4 s_xy[S_ / 2];          // (x2p,x2p+1,y2p,y2p+1) 16 KB
    __shared__ f32x2  s_z[S_ / 2];           // (z2p,z2p+1)            8 KB
    __shared__ float  s_pd[NCH][3][TILE_Q];  // partial top-3 dists    6 KB
    __shared__ int    s_pi[NCH][3][TILE_Q];  // partial top-3 idx      6 KB
    __shared__ float  s_w[3][TILE_Q];
    __shared__ int    s_idx[3][TILE_Q];

    // batch-per-XCD swizzle: blocks with bid%8==x (round-robin -> XCD x) all
    // work on batch x -> each XCD's points2 slice (2 MB) fits its 4 MB L2.
    const int b  = blockIdx.x & 7;
    const int n0 = (blockIdx.x >> 3) * TILE_Q;
    const int t = threadIdx.x;
    const int wave = t >> 6, lane = t & 63;

    // Stage xyz2 as pair-packed SoA (coalesced 8B global loads).
    const float* x2 = xyz2 + (size_t)b * 3 * S_;
    const f32x2* gx = (const f32x2*)x2;
    const f32x2* gy = (const f32x2*)(x2 + S_);
    const f32x2* gz = (const f32x2*)(x2 + 2 * S_);
    for (int p = t; p < S_ / 2; p += NTHR) {
        f32x2 px = gx[p], py = gy[p];
        s_xy[p] = make_float4(px.x, px.y, py.x, py.y);
        s_z[p]  = gz[p];
    }
    __syncthreads();

    // Phase A: wave w scans its 256-candidate chunk for 64 queries
    // (lane<->query). Two INDEPENDENT insert chains over the two contiguous
    // 128-candidate halves -> 2x ILP on the serial select chain; merged at
    // the end (lo-half indices all < hi-half -> strict '<' merge is stable).
    const int n = n0 + lane;
    const float* x1 = xyz1 + (size_t)b * 3 * N_;
    const float ax = x1[n], ay = x1[N_ + n], az = x1[2 * N_ + n];
    const f32x2 axv = {ax, ax}, ayv = {ay, ay}, azv = {az, az};

    float a0 = __builtin_inff(), a1 = __builtin_inff(), a2 = __builtin_inff();
    int ja0 = 0, ja1 = 0, ja2 = 0;
    float c0 = __builtin_inff(), c1 = __builtin_inff(), c2 = __builtin_inff();
    int jc0 = 0, jc1 = 0, jc2 = 0;

    const int pbeg = wave * (CHUNK / 2);  // 128 pairs per chunk
    const int sbeg = wave * CHUNK;
    #pragma unroll 4
    for (int j = 0; j < HPAIR; ++j) {
        float4 xyl = s_xy[pbeg + j];
        f32x2  zl  = s_z[pbeg + j];
        float4 xyh = s_xy[pbeg + HPAIR + j];
        f32x2  zh  = s_z[pbeg + HPAIR + j];

        f32x2 dxl = axv - (f32x2){xyl.x, xyl.y};
        f32x2 dyl = ayv - (f32x2){xyl.z, xyl.w};
        f32x2 dzl = azv - zl;
        f32x2 ddl = __builtin_elementwise_fma(
            dxl, dxl, __builtin_elementwise_fma(dyl, dyl, dzl * dzl));

        f32x2 dxh = axv - (f32x2){xyh.x, xyh.y};
        f32x2 dyh = ayv - (f32x2){xyh.z, xyh.w};
        f32x2 dzh = azv - zh;
        f32x2 ddh = __builtin_elementwise_fma(
            dxh, dxh, __builtin_elementwise_fma(dyh, dyh, dzh * dzh));

        const int sl = sbeg + 2 * j;
        const int sh = sbeg + 2 * HPAIR + 2 * j;
        insert3(ddl.x, sl,     a0, a1, a2, ja0, ja1, ja2);
        insert3(ddl.y, sl + 1, a0, a1, a2, ja0, ja1, ja2);
        insert3(ddh.x, sh,     c0, c1, c2, jc0, jc1, jc2);
        insert3(ddh.y, sh + 1, c0, c1, c2, jc0, jc1, jc2);
    }
    // merge hi chain into lo chain (index-stable: all hi indices larger)
    insert3(c0, jc0, a0, a1, a2, ja0, ja1, ja2);
    insert3(c1, jc1, a0, a1, a2, ja0, ja1, ja2);
    insert3(c2, jc2, a0, a1, a2, ja0, ja1, ja2);

    s_pd[wave][0][lane] = a0; s_pd[wave][1][lane] = a1; s_pd[wave][2][lane] = a2;
    s_pi[wave][0][lane] = ja0; s_pi[wave][1][lane] = ja1; s_pi[wave][2][lane] = ja2;
    __syncthreads();

    // Phase B: merge 8 chunk-triples per query (ascending chunk order =>
    // ascending index blocks => stable).
    if (t < TILE_Q) {
        float e0 = __builtin_inff(), e1 = __builtin_inff(), e2 = __builtin_inff();
        int j0 = 0, j1 = 0, j2 = 0;
        #pragma unroll
        for (int c = 0; c < NCH; ++c) {
            #pragma unroll
            for (int k = 0; k < 3; ++k)
                insert3(s_pd[c][k][t], s_pi[c][k][t], e0, e1, e2, j0, j1, j2);
        }
        float r0 = __fdiv_rn(1.0f, __fadd_rn(e0, EPS_));
        float r1 = __fdiv_rn(1.0f, __fadd_rn(e1, EPS_));
        float r2 = __fdiv_rn(1.0f, __fadd_rn(e2, EPS_));
        float rs = __fadd_rn(__fadd_rn(r0, r1), r2);
        s_w[0][t] = __fdiv_rn(r0, rs);
        s_w[1][t] = __fdiv_rn(r1, rs);
        s_w[2][t] = __fdiv_rn(r2, rs);
        s_idx[0][t] = j0; s_idx[1][t] = j1; s_idx[2][t] = j2;
    }
    __syncthreads();

    // Phase C: gather + weighted sum. One wave per query row; 64 lanes x
    // float4 covers D=256. With the batch swizzle each XCD's gather set is
    // one 2 MB slice -> L2-resident.
    const float* p2 = points2 + (size_t)b * S_ * D_;
    float* op = out + ((size_t)b * N_ + n0) * D_;
    for (int q = wave; q < TILE_Q; q += NCH) {
        float w0 = s_w[0][q], w1 = s_w[1][q], w2 = s_w[2][q];
        const float4* f0 = (const float4*)(p2 + (size_t)s_idx[0][q] * D_) + lane;
        const float4* f1 = (const float4*)(p2 + (size_t)s_idx[1][q] * D_) + lane;
        const float4* f2 = (const float4*)(p2 + (size_t)s_idx[2][q] * D_) + lane;
        float4 v0 = *f0, v1 = *f1, v2 = *f2;
        float4 r;
        r.x = w0 * v0.x + w1 * v1.x + w2 * v2.x;
        r.y = w0 * v0.y + w1 * v1.y + w2 * v2.y;
        r.z = w0 * v0.z + w1 * v1.z + w2 * v2.z;
        r.w = w0 * v0.w + w1 * v1.w + w2 * v2.w;
        *((float4*)(op + (size_t)q * D_) + lane) = r;
    }
}

extern "C" void kernel_launch(void* const* d_in, const int* in_sizes, int n_in,
                              void* d_out, int out_size, void* d_ws, size_t ws_size,
                              hipStream_t stream) {
    const float* xyz1    = (const float*)d_in[0];
    const float* xyz2    = (const float*)d_in[1];
    // d_in[2] = points1 is unused by the reference output.
    const float* points2 = (const float*)d_in[3];
    float* out = (float*)d_out;

    dim3 grid(B_ * (N_ / TILE_Q));  // 1024 blocks, 4 per CU at 512 thr
    dim3 block(NTHR);
    fp_interp_kernel<<<grid, block, 0, stream>>>(xyz1, xyz2, points2, out);
}

// Round 6
// 179.653 us; speedup vs baseline: 1.0712x; 1.0474x over previous
//
#include <hip/hip_runtime.h>

#define B_ 8
#define N_ 8192
#define S_ 2048
#define D_ 256
#define EPS_ 1e-8f
#define TILE_Q 64
#define NTHR 512
#define NCH 8
#define CHUNK (S_ / NCH)   /* 256 candidates per wave */
#define HALF (CHUNK / 2)   /* 128: two independent insert chains */

// Branchless stable top-3 insert, med3 network. Sorted invariant d0<=d1<=d2.
// Strict '<' => incumbent (earlier index) wins ties, matching jax.lax.top_k.
__device__ __forceinline__ void insert3(float dd, int s,
                                        float& d0, float& d1, float& d2,
                                        int& i0, int& i1, int& i2) {
    bool ca = dd < d0;
    bool cb = dd < d1;
    bool cc = dd < d2;
    int i2n = cb ? i1 : (cc ? s : i2);
    int i1n = ca ? i0 : (cb ? s : i1);
    int i0n = ca ? s : i0;
    d2 = fminf(d2, fmaxf(d1, dd));
    d1 = __builtin_amdgcn_fmed3f(d0, d1, dd);
    d0 = fminf(d0, dd);
    i0 = i0n; i1 = i1n; i2 = i2n;
}

__global__ __launch_bounds__(NTHR, 8) void fp_interp_kernel(
    const float* __restrict__ xyz1,     // [B,3,N]
    const float* __restrict__ xyz2,     // [B,3,S]
    const float* __restrict__ points2,  // [B,S,D]
    float* __restrict__ out)            // [B,N,D]
{
    // 32 KB tile: candidate s -> (-2*bx, -2*by, -2*bz, |b|^2).
    // rank key = |b|^2 - 2*a.b  (per-query constant |a|^2 dropped; re-added
    // for the weights in phase B — R1's expansion form, proven at 0.0156).
    // After wave w finishes scanning its chunk, rows [256w,256w+256) are dead
    // and reused to hold that wave's partial top-3 (in-order LDS ops within a
    // wave make the self-overlap safe).
    __shared__ float4 s_tile[S_];
    __shared__ float  s_w[3][TILE_Q];
    __shared__ int    s_idx[3][TILE_Q];

    // batch-per-XCD swizzle: each XCD's points2 gather set is one 2 MB slice.
    const int b  = blockIdx.x & 7;
    const int n0 = (blockIdx.x >> 3) * TILE_Q;
    const int t = threadIdx.x;
    const int wave = t >> 6, lane = t & 63;

    // Stage pre-scaled candidates (coalesced global reads, one-time cost).
    const float* x2 = xyz2 + (size_t)b * 3 * S_;
    for (int s = t; s < S_; s += NTHR) {
        float bx = x2[s], by = x2[S_ + s], bz = x2[2 * S_ + s];
        float nn = fmaf(bz, bz, fmaf(by, by, bx * bx));
        s_tile[s] = make_float4(-2.0f * bx, -2.0f * by, -2.0f * bz, nn);
    }
    __syncthreads();

    // Phase A: wave w scans its 256-candidate chunk for 64 queries
    // (lane<->query). Tile reads are wave-uniform -> ds_read_b128 broadcast.
    // 3 fma (key) + 12 (insert) per candidate; two independent chains for ILP
    // (lo-half indices all < hi-half -> strict '<' merge stays stable).
    const int n = n0 + lane;
    const float* x1 = xyz1 + (size_t)b * 3 * N_;
    const float ax = x1[n], ay = x1[N_ + n], az = x1[2 * N_ + n];

    float a0 = __builtin_inff(), a1 = __builtin_inff(), a2 = __builtin_inff();
    int ja0 = 0, ja1 = 0, ja2 = 0;
    float c0 = __builtin_inff(), c1 = __builtin_inff(), c2 = __builtin_inff();
    int jc0 = 0, jc1 = 0, jc2 = 0;

    const int sbeg = wave * CHUNK;
    #pragma unroll 8
    for (int j = 0; j < HALF; ++j) {
        float4 cl = s_tile[sbeg + j];
        float4 ch = s_tile[sbeg + HALF + j];
        float kl = fmaf(ax, cl.x, fmaf(ay, cl.y, fmaf(az, cl.z, cl.w)));
        float kh = fmaf(ax, ch.x, fmaf(ay, ch.y, fmaf(az, ch.z, ch.w)));
        insert3(kl, sbeg + j,        a0, a1, a2, ja0, ja1, ja2);
        insert3(kh, sbeg + HALF + j, c0, c1, c2, jc0, jc1, jc2);
    }
    // merge hi chain into lo (index-stable: all hi indices larger)
    insert3(c0, jc0, a0, a1, a2, ja0, ja1, ja2);
    insert3(c1, jc1, a0, a1, a2, ja0, ja1, ja2);
    insert3(c2, jc2, a0, a1, a2, ja0, ja1, ja2);

    // Write partial triple into this wave's own dead chunk region.
    {
        float* reg = (float*)&s_tile[wave * CHUNK];  // 1024 floats, ours now
        int*   regi = (int*)reg;
        reg[0 * 64 + lane] = a0;
        reg[1 * 64 + lane] = a1;
        reg[2 * 64 + lane] = a2;
        regi[256 + 0 * 64 + lane] = ja0;
        regi[256 + 1 * 64 + lane] = ja1;
        regi[256 + 2 * 64 + lane] = ja2;
    }
    __syncthreads();

    // Phase B: merge 8 chunk-triples per query (ascending chunk order =>
    // ascending index blocks => stable). Recover true distance = key + |a|^2.
    if (t < TILE_Q) {
        float e0 = __builtin_inff(), e1 = __builtin_inff(), e2 = __builtin_inff();
        int j0 = 0, j1 = 0, j2 = 0;
        #pragma unroll
        for (int c = 0; c < NCH; ++c) {
            const float* rc = (const float*)&s_tile[c * CHUNK];
            const int*   rci = (const int*)rc;
            #pragma unroll
            for (int k = 0; k < 3; ++k)
                insert3(rc[k * 64 + t], rci[256 + k * 64 + t],
                        e0, e1, e2, j0, j1, j2);
        }
        const int nq = n0 + t;
        float qx = x1[nq], qy = x1[N_ + nq], qz = x1[2 * N_ + nq];
        float n1 = fmaf(qz, qz, fmaf(qy, qy, qx * qx));
        float r0 = __fdiv_rn(1.0f, __fadd_rn(__fadd_rn(e0, n1), EPS_));
        float r1 = __fdiv_rn(1.0f, __fadd_rn(__fadd_rn(e1, n1), EPS_));
        float r2 = __fdiv_rn(1.0f, __fadd_rn(__fadd_rn(e2, n1), EPS_));
        float rs = __fadd_rn(__fadd_rn(r0, r1), r2);
        s_w[0][t] = __fdiv_rn(r0, rs);
        s_w[1][t] = __fdiv_rn(r1, rs);
        s_w[2][t] = __fdiv_rn(r2, rs);
        s_idx[0][t] = j0; s_idx[1][t] = j1; s_idx[2][t] = j2;
    }
    __syncthreads();

    // Phase C: gather + weighted sum. One wave per query row; 64 lanes x
    // float4 covers D=256. Gather set is L2-resident per XCD.
    const float* p2 = points2 + (size_t)b * S_ * D_;
    float* op = out + ((size_t)b * N_ + n0) * D_;
    for (int q = wave; q < TILE_Q; q += NCH) {
        float w0 = s_w[0][q], w1 = s_w[1][q], w2 = s_w[2][q];
        const float4* f0 = (const float4*)(p2 + (size_t)s_idx[0][q] * D_) + lane;
        const float4* f1 = (const float4*)(p2 + (size_t)s_idx[1][q] * D_) + lane;
        const float4* f2 = (const float4*)(p2 + (size_t)s_idx[2][q] * D_) + lane;
        float4 v0 = *f0, v1 = *f1, v2 = *f2;
        float4 r;
        r.x = w0 * v0.x + w1 * v1.x + w2 * v2.x;
        r.y = w0 * v0.y + w1 * v1.y + w2 * v2.y;
        r.z = w0 * v0.z + w1 * v1.z + w2 * v2.z;
        r.w = w0 * v0.w + w1 * v1.w + w2 * v2.w;
        *((float4*)(op + (size_t)q * D_) + lane) = r;
    }
}

extern "C" void kernel_launch(void* const* d_in, const int* in_sizes, int n_in,
                              void* d_out, int out_size, void* d_ws, size_t ws_size,
                              hipStream_t stream) {
    const float* xyz1    = (const float*)d_in[0];
    const float* xyz2    = (const float*)d_in[1];
    // d_in[2] = points1 is unused by the reference output.
    const float* points2 = (const float*)d_in[3];
    float* out = (float*)d_out;

    dim3 grid(B_ * (N_ / TILE_Q));  // 1024 blocks, 4 per CU at 512 thr
    dim3 block(NTHR);
    fp_interp_kernel<<<grid, block, 0, stream>>>(xyz1, xyz2, points2, out);
}